// Round 1
// baseline (1204.232 us; speedup 1.0000x reference)
//
#include <hip/hip_runtime.h>

#define BATCH 1000000
#define C 64
#define D 128
#define NPAIRS 2016   // 64*63/2
#define CHUNK 8       // rows per wave per iteration (MLP unroll)

// ---------------- stage 1: streaming pass over features ----------------
// Grid-stride by wave over 8-row chunks. Lane l handles dims l and l+64.
// All 16 row-loads of a chunk are issued before any use -> ~64KB in flight/CU.
// LDS accumulator sS[64][128]: atomic address t*128+l -> bank l%32 -> 2-way (free).
// Class counts: lane-indexed register histogram (lane c counts class c), one
// LDS atomic per wave at the end instead of one per row.
__global__ __launch_bounds__(1024) void stage1_kernel(
        const float* __restrict__ feat, const int* __restrict__ targets,
        float* __restrict__ pSums, float* __restrict__ pCnt,
        double* __restrict__ pSq, int nB) {
    __shared__ float sS[C * D];     // 32 KB
    __shared__ float sC[C];
    __shared__ float sWave[16];

    const int tid = threadIdx.x;
    for (int i = tid; i < C * D; i += 1024) sS[i] = 0.0f;
    if (tid < C) sC[tid] = 0.0f;
    __syncthreads();

    const int lane = tid & 63;
    const int wid  = tid >> 6;                 // 0..15
    const int gwave = blockIdx.x * 16 + wid;
    const int nwaves = nB * 16;
    const int nchunks = BATCH / CHUNK;         // 125000, exact

    float lsq  = 0.0f;
    float lcnt = 0.0f;
    for (int ch = gwave; ch < nchunks; ch += nwaves) {
        // wave-uniform scalar base -> targets become s_load, feat base in SGPRs
        const int r0 = __builtin_amdgcn_readfirstlane(ch) * CHUNK;

        int   t[CHUNK];
        float f0[CHUNK], f1[CHUNK];
#pragma unroll
        for (int u = 0; u < CHUNK; u++) t[u] = targets[r0 + u];
#pragma unroll
        for (int u = 0; u < CHUNK; u++) {
            const float* row = feat + (size_t)(r0 + u) * D;
            f0[u] = row[lane];
            f1[u] = row[lane + 64];
        }
#pragma unroll
        for (int u = 0; u < CHUNK; u++) {
            lsq  += f0[u] * f0[u] + f1[u] * f1[u];
            lcnt += (lane == t[u]) ? 1.0f : 0.0f;   // register histogram, no atomic
            atomicAdd(&sS[t[u] * D + lane],      f0[u]);
            atomicAdd(&sS[t[u] * D + 64 + lane], f1[u]);
        }
    }
    atomicAdd(&sC[lane], lcnt);    // one per wave

    // wave-level reduce of lsq (width 64)
    for (int off = 32; off > 0; off >>= 1)
        lsq += __shfl_down(lsq, off, 64);
    if (lane == 0) sWave[wid] = lsq;
    __syncthreads();

    if (tid == 0) {
        double s = 0.0;
        for (int w = 0; w < 16; w++) s += (double)sWave[w];
        pSq[blockIdx.x] = s;
    }

    // flush deterministic per-block partials (fully overwrites its region)
    float* dst = pSums + (size_t)blockIdx.x * (C * D);
    for (int i = tid; i < C * D; i += 1024) dst[i] = sS[i];
    if (tid < C) pCnt[blockIdx.x * C + tid] = sC[tid];
}

// ---------------- stage 2: reduce partials -> centers, counts, w_c ----------------
// 32 blocks x 256 threads: thread owns one column q of the [nB][C*D] partials
// (coalesced 256B/wave per b-iteration). Counts reduced redundantly per block
// (64KB of reads, trivial). Per-class w_c reduced over the 128 dims in-block.
__global__ __launch_bounds__(256) void stage2_kernel(
        const float* __restrict__ pSums, const float* __restrict__ pCnt,
        float* __restrict__ centers, float* __restrict__ wc, int nB) {
    __shared__ float scnt[C];
    __shared__ float sred[256];
    const int tid = threadIdx.x;
    const int q = blockIdx.x * 256 + tid;      // column 0..8191

    // counts reduction (all 64 classes, 4-way split over partial blocks)
    {
        const int c = tid & 63;
        const int g = tid >> 6;                // 0..3
        float cp = 0.0f;
        for (int b = g; b < nB; b += 4) cp += pCnt[b * C + c];
        sred[tid] = cp;
        __syncthreads();
        if (tid < C)
            scnt[tid] = sred[tid] + sred[tid + 64] + sred[tid + 128] + sred[tid + 192];
        __syncthreads();
    }

    float s = 0.0f;
#pragma unroll 4
    for (int b = 0; b < nB; b++)
        s += pSums[(size_t)b * (C * D) + q];

    const float cnt = scnt[q >> 7];
    const float cc  = cnt < 1.0f ? 1.0f : cnt;
    const float ctr = s / cc;
    centers[q] = ctr;

    // w_c contribution: 2*sums*center - cnt*center^2  (== cnt*||c||^2 when cnt>=1)
    sred[tid] = 2.0f * s * ctr - cnt * ctr * ctr;
    __syncthreads();
    for (int off = 64; off > 0; off >>= 1) {
        if ((tid & 127) < off) sred[tid] += sred[tid + off];
        __syncthreads();
    }
    if ((tid & 127) == 0) wc[q >> 7] = sred[tid];   // tid==0 and tid==128
}

// ---------------- stage 3: pairwise hinge + final combine ----------------
__global__ __launch_bounds__(256) void stage3_kernel(
        const float* __restrict__ centers, const float* __restrict__ wc,
        const double* __restrict__ pSq, float* __restrict__ out, int nB) {
    __shared__ float sCtr[C * 129];   // +1 pad: bank (i+d)%32 across lanes -> spread
    __shared__ double dred[256];

    const int tid = threadIdx.x;
    for (int idx = tid; idx < C * D; idx += 256) {
        const int i = idx >> 7;
        const int d = idx & 127;
        sCtr[i * 129 + d] = centers[idx];
    }
    __syncthreads();

    // pairwise hinge over upper triangle
    float acc = 0.0f;
    for (int q = tid; q < C * C; q += 256) {
        const int i = q >> 6;
        const int j = q & 63;
        if (j > i) {
            const float* ci = sCtr + i * 129;
            const float* cj = sCtr + j * 129;
            float d2 = 0.0f;
            for (int d = 0; d < D; d++) {
                const float df = ci[d] - cj[d];
                d2 += df * df;
            }
            float h = 2.0f - d2;            // MARGIN = 2.0
            if (h < 0.0f) h = 0.0f;
            const float w = (i == 1 && j == 2) ? 2.0f : 1.0f;
            acc += w * h;
        }
    }

    // sumsq partials
    double dacc = 0.0;
    for (int b = tid; b < nB; b += 256) dacc += pSq[b];

    // per-class w_c
    float wacc = 0.0f;
    if (tid < C) wacc = wc[tid];

    // combined: (sumsq - sum_wc)/B + hinge_sum/NPAIRS
    dred[tid] = (dacc - (double)wacc) * (1.0 / (double)BATCH)
              + (double)acc * (1.0 / (double)NPAIRS);
    __syncthreads();
    for (int off = 128; off > 0; off >>= 1) {
        if (tid < off) dred[tid] += dred[tid + off];
        __syncthreads();
    }
    if (tid == 0) out[0] = (float)dred[0];
}

extern "C" void kernel_launch(void* const* d_in, const int* in_sizes, int n_in,
                              void* d_out, int out_size, void* d_ws, size_t ws_size,
                              hipStream_t stream) {
    const float* feat    = (const float*)d_in[0];
    const int*   targets = (const int*)d_in[1];
    float* out = (float*)d_out;

    // pick nB (stage-1 grid) so partials fit in ws
    int nB = 256;
    while (nB > 1) {
        size_t need = (size_t)nB * (C * D + C) * sizeof(float)   // partial sums + counts
                    + (size_t)nB * sizeof(double)                // partial sumsq
                    + (size_t)(C * D + C) * sizeof(float) + 64;  // centers + wc
        if (need <= ws_size) break;
        nB >>= 1;
    }

    float*  pSums   = (float*)d_ws;                        // [nB][C][D]
    float*  pCnt    = pSums + (size_t)nB * C * D;          // [nB][C]
    double* pSq     = (double*)(pCnt + (size_t)nB * C);    // [nB]  (offset 8-aligned)
    float*  centers = (float*)(pSq + nB);                  // [C][D]
    float*  wcv     = centers + C * D;                     // [C]

    stage1_kernel<<<nB, 1024, 0, stream>>>(feat, targets, pSums, pCnt, pSq, nB);
    stage2_kernel<<<(C * D) / 256, 256, 0, stream>>>(pSums, pCnt, centers, wcv, nB);
    stage3_kernel<<<1, 256, 0, stream>>>(centers, wcv, pSq, out, nB);
}

// Round 2
// 803.392 us; speedup vs baseline: 1.4989x; 1.4989x over previous
//
#include <hip/hip_runtime.h>

#define BATCH 1000000
#define C 64
#define D 128
#define NPAIRS 2016   // 64*63/2
#define CHUNK 16      // rows per block per pipeline stage

// ---------------- stage 1: streaming pass over features ----------------
// 128-thread blocks. Thread tid exclusively owns accumulator column tid:
// sAcc[c*128 + tid] for all c. Per row, the block loads feat[r*128 + 0..127]
// (512 B coalesced) and each thread does a plain LDS read-add-write to its
// own column -- NO atomics, no races (waves own disjoint columns; the DS
// pipe is in-order per wave, so same-address row sequences are correct).
// Chunks of 16 rows double-buffered in registers; next chunk's global loads
// are pinned above the RMW chain via sched_barrier so HBM latency hides.
__global__ __launch_bounds__(128) void stage1_kernel(
        const float* __restrict__ feat, const int* __restrict__ targets,
        float* __restrict__ pSums, float* __restrict__ pCnt,
        double* __restrict__ pSq, int nB) {
    __shared__ float sAcc[C * D];   // 32 KB; column tid owned by thread tid
    __shared__ double sRed[128];

    const int tid = threadIdx.x;
    for (int i = tid; i < C * D; i += 128) sAcc[i] = 0.0f;  // column tid: self-owned
    __syncthreads();

    const int nchunks = BATCH / CHUNK;   // 62500, exact

    float lsq  = 0.0f;
    float lcnt = 0.0f;

    float fA[CHUNK], fB[CHUNK];
    int   tA[CHUNK], tB[CHUNK];

    int ch = blockIdx.x;                 // nB <= 62500 always -> every block has work
    {
        const int r0 = ch * CHUNK;       // block-uniform -> scalar target loads
#pragma unroll
        for (int u = 0; u < CHUNK; u++) tA[u] = targets[r0 + u];
#pragma unroll
        for (int u = 0; u < CHUNK; u++) fA[u] = feat[(size_t)(r0 + u) * D + tid];
    }

    for (;;) {
        const int chN = ch + nB;
        const bool more = chN < nchunks;
        if (more) {
            const int r0 = chN * CHUNK;
#pragma unroll
            for (int u = 0; u < CHUNK; u++) tB[u] = targets[r0 + u];
#pragma unroll
            for (int u = 0; u < CHUNK; u++) fB[u] = feat[(size_t)(r0 + u) * D + tid];
        }
        __builtin_amdgcn_sched_barrier(0);   // keep next-chunk loads above the chain

        // RMW chain on current chunk (exclusive column -> plain LDS ops)
#pragma unroll
        for (int u = 0; u < CHUNK; u++) {
            const float f = fA[u];
            lsq  += f * f;
            lcnt += (tA[u] == tid) ? 1.0f : 0.0f;   // tid<64 lanes build histogram
            sAcc[tA[u] * D + tid] += f;
        }

        if (!more) break;
#pragma unroll
        for (int u = 0; u < CHUNK; u++) { fA[u] = fB[u]; tA[u] = tB[u]; }
        ch = chN;
    }

    // block reduce of sum-of-squares in double
    __syncthreads();
    sRed[tid] = (double)lsq;
    __syncthreads();
    for (int off = 64; off > 0; off >>= 1) {
        if (tid < off) sRed[tid] += sRed[tid + off];
        __syncthreads();
    }
    if (tid == 0) pSq[blockIdx.x] = sRed[0];

    // flush deterministic per-block partials (fully overwrites its region)
    float* dst = pSums + (size_t)blockIdx.x * (C * D);
    for (int i = tid; i < C * D; i += 128) dst[i] = sAcc[i];
    if (tid < C) pCnt[blockIdx.x * C + tid] = lcnt;
}

// ---------------- stage 2: reduce partials -> centers, counts, w_c ----------------
// 32 blocks x 256 threads: thread owns one column q of the [nB][C*D] partials
// (coalesced per b-iteration). Counts reduced redundantly per block.
__global__ __launch_bounds__(256) void stage2_kernel(
        const float* __restrict__ pSums, const float* __restrict__ pCnt,
        float* __restrict__ centers, float* __restrict__ wc, int nB) {
    __shared__ float scnt[C];
    __shared__ float sred[256];
    const int tid = threadIdx.x;
    const int q = blockIdx.x * 256 + tid;      // column 0..8191

    // counts reduction (all 64 classes, 4-way split over partial blocks)
    {
        const int c = tid & 63;
        const int g = tid >> 6;                // 0..3
        float cp = 0.0f;
        for (int b = g; b < nB; b += 4) cp += pCnt[b * C + c];
        sred[tid] = cp;
        __syncthreads();
        if (tid < C)
            scnt[tid] = sred[tid] + sred[tid + 64] + sred[tid + 128] + sred[tid + 192];
        __syncthreads();
    }

    float s = 0.0f;
#pragma unroll 4
    for (int b = 0; b < nB; b++)
        s += pSums[(size_t)b * (C * D) + q];

    const float cnt = scnt[q >> 7];
    const float cc  = cnt < 1.0f ? 1.0f : cnt;
    const float ctr = s / cc;
    centers[q] = ctr;

    // w_c contribution: 2*sums*center - cnt*center^2  (== cnt*||c||^2 when cnt>=1)
    sred[tid] = 2.0f * s * ctr - cnt * ctr * ctr;
    __syncthreads();
    for (int off = 64; off > 0; off >>= 1) {
        if ((tid & 127) < off) sred[tid] += sred[tid + off];
        __syncthreads();
    }
    if ((tid & 127) == 0) wc[q >> 7] = sred[tid];   // tid==0 and tid==128
}

// ---------------- stage 3: pairwise hinge + final combine ----------------
__global__ __launch_bounds__(256) void stage3_kernel(
        const float* __restrict__ centers, const float* __restrict__ wc,
        const double* __restrict__ pSq, float* __restrict__ out, int nB) {
    __shared__ float sCtr[C * 129];   // +1 pad
    __shared__ double dred[256];

    const int tid = threadIdx.x;
    for (int idx = tid; idx < C * D; idx += 256) {
        const int i = idx >> 7;
        const int d = idx & 127;
        sCtr[i * 129 + d] = centers[idx];
    }
    __syncthreads();

    // pairwise hinge over upper triangle
    float acc = 0.0f;
    for (int q = tid; q < C * C; q += 256) {
        const int i = q >> 6;
        const int j = q & 63;
        if (j > i) {
            const float* ci = sCtr + i * 129;
            const float* cj = sCtr + j * 129;
            float d2 = 0.0f;
            for (int d = 0; d < D; d++) {
                const float df = ci[d] - cj[d];
                d2 += df * df;
            }
            float h = 2.0f - d2;            // MARGIN = 2.0
            if (h < 0.0f) h = 0.0f;
            const float w = (i == 1 && j == 2) ? 2.0f : 1.0f;
            acc += w * h;
        }
    }

    // sumsq partials
    double dacc = 0.0;
    for (int b = tid; b < nB; b += 256) dacc += pSq[b];

    // per-class w_c
    float wacc = 0.0f;
    if (tid < C) wacc = wc[tid];

    // combined: (sumsq - sum_wc)/B + hinge_sum/NPAIRS
    dred[tid] = (dacc - (double)wacc) * (1.0 / (double)BATCH)
              + (double)acc * (1.0 / (double)NPAIRS);
    __syncthreads();
    for (int off = 128; off > 0; off >>= 1) {
        if (tid < off) dred[tid] += dred[tid + off];
        __syncthreads();
    }
    if (tid == 0) out[0] = (float)dred[0];
}

extern "C" void kernel_launch(void* const* d_in, const int* in_sizes, int n_in,
                              void* d_out, int out_size, void* d_ws, size_t ws_size,
                              hipStream_t stream) {
    const float* feat    = (const float*)d_in[0];
    const int*   targets = (const int*)d_in[1];
    float* out = (float*)d_out;

    // pick nB (stage-1 grid) so partials fit in ws; prefer 1024 (4 blocks/CU)
    int nB = 1024;
    while (nB > 1) {
        size_t need = (size_t)nB * (C * D + C) * sizeof(float)   // partial sums + counts
                    + (size_t)nB * sizeof(double)                // partial sumsq
                    + (size_t)(C * D + C) * sizeof(float) + 64;  // centers + wc
        if (need <= ws_size) break;
        nB >>= 1;
    }

    float*  pSums   = (float*)d_ws;                        // [nB][C][D]
    float*  pCnt    = pSums + (size_t)nB * C * D;          // [nB][C]
    double* pSq     = (double*)(pCnt + (size_t)nB * C);    // [nB]  (8-aligned)
    float*  centers = (float*)(pSq + nB);                  // [C][D]
    float*  wcv     = centers + C * D;                     // [C]

    stage1_kernel<<<nB, 128, 0, stream>>>(feat, targets, pSums, pCnt, pSq, nB);
    stage2_kernel<<<(C * D) / 256, 256, 0, stream>>>(pSums, pCnt, centers, wcv, nB);
    stage3_kernel<<<1, 256, 0, stream>>>(centers, wcv, pSq, out, nB);
}

// Round 3
// 775.463 us; speedup vs baseline: 1.5529x; 1.0360x over previous
//
#include <hip/hip_runtime.h>
#include <stdint.h>

#define BATCH 1000000
#define C 64
#define D 128
#define NPAIRS 2016            // 64*63/2
#define CHUNK 16               // rows per staged chunk (8 KB)
#define NCHUNKS (BATCH / CHUNK) // 62500, exact

typedef __attribute__((address_space(1))) const uint8_t ga_u8;
typedef __attribute__((address_space(3))) uint8_t ls_u8;

// Stage one 16-row chunk (8 KB) into LDS via global_load_lds width-16.
// Wave w covers bytes [w*4096, (w+1)*4096): 4 instrs x 1 KB. HW writes lane l
// at ldsbase + l*16; global src per-lane matches linearly (guide §5 caveat).
__device__ __forceinline__ void stage_chunk(const float* feat, int chunk,
                                            float* stageBase, int wid, int lane) {
    const uint8_t* g = (const uint8_t*)feat + (size_t)chunk * (CHUNK * D * 4)
                     + wid * 4096 + lane * 16;
    uint8_t* l = (uint8_t*)stageBase + wid * 4096;
#pragma unroll
    for (int i = 0; i < 4; i++) {
        __builtin_amdgcn_global_load_lds((const ga_u8*)(g + i * 1024),
                                         (ls_u8*)(l + i * 1024), 16, 0, 0);
    }
}

// ---------------- stage 1: streaming pass over features ----------------
// 128-thread blocks; thread tid exclusively owns accumulator column tid
// (sAcc[c*128+tid] for all c) -> plain LDS RMW, no atomics, no races.
// Chunks DMA'd global->LDS (no VGPR staging), double-buffered with counted
// vmcnt(4) + raw s_barrier so prefetch stays in flight across the barrier.
__global__ __launch_bounds__(128) void stage1_kernel(
        const float* __restrict__ feat, const int* __restrict__ targets,
        float* __restrict__ pSums, float* __restrict__ pCnt,
        double* __restrict__ pSq, int nB) {
    __shared__ float sAcc[C * D];             // 32 KB, column tid owned by thread tid
    __shared__ float sStage[2][CHUNK * D];    // 2 x 8 KB DMA staging
    __shared__ double sRed[128];

    const int tid  = threadIdx.x;
    const int lane = tid & 63;
    const int wid  = tid >> 6;                // 0..1

    for (int i = tid; i < C * D; i += 128) sAcc[i] = 0.0f;
    __syncthreads();

    float lsq  = 0.0f;
    float lcnt = 0.0f;

    int ch = blockIdx.x;                      // nB << NCHUNKS: every block has work
    stage_chunk(feat, ch, sStage[0], wid, lane);

    int buf = 0;
    for (;;) {
        const int chN = ch + nB;
        const bool more = chN < NCHUNKS;

        // targets for current chunk (block-uniform -> scalar loads), issued
        // before the wait so s_load latency hides under it
        int tloc[CHUNK];
        const int r0 = ch * CHUNK;
#pragma unroll
        for (int u = 0; u < CHUNK; u++) tloc[u] = targets[r0 + u];

        if (more) stage_chunk(feat, chN, sStage[buf ^ 1], wid, lane);

        // wait for CURRENT buf's 4 DMA instrs (leave the 4 just-issued in flight)
        if (more) asm volatile("s_waitcnt vmcnt(4)" ::: "memory");
        else      asm volatile("s_waitcnt vmcnt(0)" ::: "memory");
        __builtin_amdgcn_s_barrier();         // both waves' DMAs for buf done

        const float* st = sStage[buf];
#pragma unroll
        for (int u = 0; u < CHUNK; u++) {
            const int t = tloc[u];
            const float f = st[u * D + tid];
            lsq  += f * f;
            lcnt += (t == tid) ? 1.0f : 0.0f;   // tid<64 builds the histogram
            sAcc[t * D + tid] += f;
        }

        if (!more) break;
        // protect buf: next iteration's prefetch overwrites it; make sure all
        // waves finished their ds_reads of buf first
        asm volatile("s_waitcnt lgkmcnt(0)" ::: "memory");
        __builtin_amdgcn_s_barrier();
        ch = chN;
        buf ^= 1;
    }

    // block reduce of sum-of-squares in double
    __syncthreads();
    sRed[tid] = (double)lsq;
    __syncthreads();
    for (int off = 64; off > 0; off >>= 1) {
        if (tid < off) sRed[tid] += sRed[tid + off];
        __syncthreads();
    }
    if (tid == 0) pSq[blockIdx.x] = sRed[0];

    // flush deterministic per-block partials (fully overwrites its region)
    float* dst = pSums + (size_t)blockIdx.x * (C * D);
    for (int i = tid; i < C * D; i += 128) dst[i] = sAcc[i];
    if (tid < C) pCnt[blockIdx.x * C + tid] = lcnt;
}

// ---------------- stage 2: reduce partials -> centers, counts, w_c ----------------
// 32 blocks x 256 threads: thread owns one column q of the [nB][C*D] partials
// (coalesced per b-iteration). Counts reduced redundantly per block.
__global__ __launch_bounds__(256) void stage2_kernel(
        const float* __restrict__ pSums, const float* __restrict__ pCnt,
        float* __restrict__ centers, float* __restrict__ wc, int nB) {
    __shared__ float scnt[C];
    __shared__ float sred[256];
    const int tid = threadIdx.x;
    const int q = blockIdx.x * 256 + tid;      // column 0..8191

    // counts reduction (all 64 classes, 4-way split over partial blocks)
    {
        const int c = tid & 63;
        const int g = tid >> 6;                // 0..3
        float cp = 0.0f;
        for (int b = g; b < nB; b += 4) cp += pCnt[b * C + c];
        sred[tid] = cp;
        __syncthreads();
        if (tid < C)
            scnt[tid] = sred[tid] + sred[tid + 64] + sred[tid + 128] + sred[tid + 192];
        __syncthreads();
    }

    float s = 0.0f;
#pragma unroll 4
    for (int b = 0; b < nB; b++)
        s += pSums[(size_t)b * (C * D) + q];

    const float cnt = scnt[q >> 7];
    const float cc  = cnt < 1.0f ? 1.0f : cnt;
    const float ctr = s / cc;
    centers[q] = ctr;

    // w_c contribution: 2*sums*center - cnt*center^2  (== cnt*||c||^2 when cnt>=1)
    sred[tid] = 2.0f * s * ctr - cnt * ctr * ctr;
    __syncthreads();
    for (int off = 64; off > 0; off >>= 1) {
        if ((tid & 127) < off) sred[tid] += sred[tid + off];
        __syncthreads();
    }
    if ((tid & 127) == 0) wc[q >> 7] = sred[tid];   // tid==0 and tid==128
}

// ---------------- stage 3: pairwise hinge + final combine ----------------
__global__ __launch_bounds__(256) void stage3_kernel(
        const float* __restrict__ centers, const float* __restrict__ wc,
        const double* __restrict__ pSq, float* __restrict__ out, int nB) {
    __shared__ float sCtr[C * 129];   // +1 pad
    __shared__ double dred[256];

    const int tid = threadIdx.x;
    for (int idx = tid; idx < C * D; idx += 256) {
        const int i = idx >> 7;
        const int d = idx & 127;
        sCtr[i * 129 + d] = centers[idx];
    }
    __syncthreads();

    // pairwise hinge over upper triangle
    float acc = 0.0f;
    for (int q = tid; q < C * C; q += 256) {
        const int i = q >> 6;
        const int j = q & 63;
        if (j > i) {
            const float* ci = sCtr + i * 129;
            const float* cj = sCtr + j * 129;
            float d2 = 0.0f;
            for (int d = 0; d < D; d++) {
                const float df = ci[d] - cj[d];
                d2 += df * df;
            }
            float h = 2.0f - d2;            // MARGIN = 2.0
            if (h < 0.0f) h = 0.0f;
            const float w = (i == 1 && j == 2) ? 2.0f : 1.0f;
            acc += w * h;
        }
    }

    // sumsq partials
    double dacc = 0.0;
    for (int b = tid; b < nB; b += 256) dacc += pSq[b];

    // per-class w_c
    float wacc = 0.0f;
    if (tid < C) wacc = wc[tid];

    // combined: (sumsq - sum_wc)/B + hinge_sum/NPAIRS
    dred[tid] = (dacc - (double)wacc) * (1.0 / (double)BATCH)
              + (double)acc * (1.0 / (double)NPAIRS);
    __syncthreads();
    for (int off = 128; off > 0; off >>= 1) {
        if (tid < off) dred[tid] += dred[tid + off];
        __syncthreads();
    }
    if (tid == 0) out[0] = (float)dred[0];
}

extern "C" void kernel_launch(void* const* d_in, const int* in_sizes, int n_in,
                              void* d_out, int out_size, void* d_ws, size_t ws_size,
                              hipStream_t stream) {
    const float* feat    = (const float*)d_in[0];
    const int*   targets = (const int*)d_in[1];
    float* out = (float*)d_out;

    // nB = 768: 3 blocks/CU (49.5 KB LDS each), partials = 25 MB in ws
    int nB = 768;
    while (nB > 1) {
        size_t need = (size_t)nB * (C * D + C) * sizeof(float)   // partial sums + counts
                    + (size_t)nB * sizeof(double)                // partial sumsq
                    + (size_t)(C * D + C) * sizeof(float) + 64;  // centers + wc
        if (need <= ws_size) break;
        nB >>= 1;
    }

    float*  pSums   = (float*)d_ws;                        // [nB][C][D]
    float*  pCnt    = pSums + (size_t)nB * C * D;          // [nB][C]
    double* pSq     = (double*)(pCnt + (size_t)nB * C);    // [nB]  (8-aligned)
    float*  centers = (float*)(pSq + nB);                  // [C][D]
    float*  wcv     = centers + C * D;                     // [C]

    stage1_kernel<<<nB, 128, 0, stream>>>(feat, targets, pSums, pCnt, pSq, nB);
    stage2_kernel<<<(C * D) / 256, 256, 0, stream>>>(pSums, pCnt, centers, wcv, nB);
    stage3_kernel<<<1, 256, 0, stream>>>(centers, wcv, pSq, out, nB);
}

// Round 4
// 711.907 us; speedup vs baseline: 1.6916x; 1.0893x over previous
//
#include <hip/hip_runtime.h>
#include <stdint.h>

#define BATCH 1000000
#define C 64
#define D 128
#define NPAIRS 2016          // 64*63/2
#define NT 250               // sort tiles
#define TILE 4000            // rows per tile; NT*TILE == BATCH exactly
#define SUB 16               // sub-segments per class in accum
#define NACC (C * SUB)       // 1024 accum blocks

// ---------------- K1: per-tile class histogram ----------------
// Block b owns rows [b*TILE, (b+1)*TILE). Coalesced int reads, LDS int atomics
// (native ds_add). Writes deterministic per-block histogram (no init needed).
__global__ __launch_bounds__(256) void hist_kernel(
        const int* __restrict__ targets, int* __restrict__ bHist) {
    __shared__ int h[C];
    const int tid = threadIdx.x;
    if (tid < C) h[tid] = 0;
    __syncthreads();
    const int base = blockIdx.x * TILE;
    for (int i = tid; i < TILE; i += 256)
        atomicAdd(&h[targets[base + i]], 1);
    __syncthreads();
    if (tid < C) bHist[blockIdx.x * C + tid] = h[tid];
}

// ---------------- K2: scan -> counts, class offsets, per-(tile,class) bases ----
__global__ __launch_bounds__(64) void scan_kernel(
        const int* __restrict__ bHist, int* __restrict__ bBase,
        int* __restrict__ counts, int* __restrict__ off) {
    __shared__ int sCnt[C];
    __shared__ int sOff[C + 1];
    const int c = threadIdx.x;           // 0..63, one wave
    int run = 0;
    for (int b = 0; b < NT; b++) run += bHist[b * C + c];
    sCnt[c] = run;
    counts[c] = run;
    __syncthreads();
    if (c == 0) {
        int acc = 0;
        for (int k = 0; k < C; k++) { sOff[k] = acc; acc += sCnt[k]; }
        sOff[C] = acc;
    }
    __syncthreads();
    off[c] = sOff[c];
    if (c == 0) off[C] = sOff[C];
    int base = sOff[c];
    for (int b = 0; b < NT; b++) {
        bBase[b * C + c] = base;
        base += bHist[b * C + c];
    }
}

// ---------------- K3: scatter row indices class-sorted ----------------
// Same tiling as K1. Rank within (tile,class) via LDS int atomic; position =
// bBase[tile][class] + rank. Every slot in idxSorted written exactly once.
__global__ __launch_bounds__(256) void scatter_kernel(
        const int* __restrict__ targets, const int* __restrict__ bBase,
        int* __restrict__ idxSorted) {
    __shared__ int gbase[C];
    __shared__ int lrank[C];
    const int tid = threadIdx.x;
    if (tid < C) { gbase[tid] = bBase[blockIdx.x * C + tid]; lrank[tid] = 0; }
    __syncthreads();
    const int base = blockIdx.x * TILE;
    for (int i = tid; i < TILE; i += 256) {
        const int r = base + i;
        const int t = targets[r];
        const int rk = atomicAdd(&lrank[t], 1);
        idxSorted[gbase[t] + rk] = r;
    }
}

// ---------------- K4: class-contiguous accumulate (the streaming pass) -------
// Block = (class c, subsegment j); 256 threads = 2 row-slots x 128 dims.
// acc lives in a REGISTER (one class per block -> no scatter, no LDS RMW, no
// aliasing). 8 independent row gathers in flight per wave; 16 waves/CU.
__global__ __launch_bounds__(256) void accum_kernel(
        const float* __restrict__ feat, const int* __restrict__ idxSorted,
        const int* __restrict__ off, float* __restrict__ pSums,
        double* __restrict__ pSq) {
    const int tid  = threadIdx.x;
    const int d    = tid & 127;
    const int slot = tid >> 7;           // 0..1 (wave-uniform)
    const int c    = blockIdx.x / SUB;
    const int j    = blockIdx.x % SUB;
    const int cs   = off[c];
    const int ce   = off[c + 1];
    const int n    = ce - cs;
    const int per  = (n + SUB - 1) / SUB;
    const int s0   = cs + j * per;
    const int s1   = min(s0 + per, ce);

    float acc = 0.0f, lsq = 0.0f;
    int i = s0;
    // main: 16 rows per iteration, slot s takes [i+8s, i+8s+8)
    for (; i + 16 <= s1; i += 16) {
        int id[8];
#pragma unroll
        for (int k = 0; k < 8; k++) id[k] = idxSorted[i + 8 * slot + k];
#pragma unroll
        for (int k = 0; k < 8; k++) {
            const float f = feat[(size_t)id[k] * D + d];
            acc += f;
            lsq += f * f;
        }
    }
    // tail: alternate rows between slots (disjoint partition)
    for (int r = i + slot; r < s1; r += 2) {
        const float f = feat[(size_t)idxSorted[r] * D + d];
        acc += f;
        lsq += f * f;
    }

    __shared__ float  sA[256];
    __shared__ double sD[256];
    sA[tid] = acc;
    sD[tid] = (double)lsq;
    __syncthreads();
    if (slot == 0) pSums[(size_t)blockIdx.x * D + d] = sA[tid] + sA[tid + 128];
    for (int o = 128; o > 0; o >>= 1) {
        if (tid < o) sD[tid] += sD[tid + o];
        __syncthreads();
    }
    if (tid == 0) pSq[blockIdx.x] = sD[0];
}

// ---------------- K5: centers + w_c ----------------
__global__ __launch_bounds__(128) void centers_kernel(
        const float* __restrict__ pSums, const int* __restrict__ counts,
        float* __restrict__ centers, float* __restrict__ wc) {
    __shared__ float sred[128];
    const int c = blockIdx.x;
    const int d = threadIdx.x;
    float s = 0.0f;
#pragma unroll
    for (int j = 0; j < SUB; j++)
        s += pSums[(size_t)(c * SUB + j) * D + d];
    const float cnt = (float)counts[c];
    const float cc  = cnt < 1.0f ? 1.0f : cnt;
    const float ctr = s / cc;
    centers[c * D + d] = ctr;
    // w_c contribution: 2*sums*center - cnt*center^2
    sred[d] = 2.0f * s * ctr - cnt * ctr * ctr;
    __syncthreads();
    for (int o = 64; o > 0; o >>= 1) {
        if (d < o) sred[d] += sred[d + o];
        __syncthreads();
    }
    if (d == 0) wc[c] = sred[0];
}

// ---------------- K6: pairwise hinge + final combine ----------------
__global__ __launch_bounds__(256) void stage3_kernel(
        const float* __restrict__ centers, const float* __restrict__ wc,
        const double* __restrict__ pSq, float* __restrict__ out, int nSq) {
    __shared__ float sCtr[C * 129];   // +1 pad
    __shared__ double dred[256];

    const int tid = threadIdx.x;
    for (int idx = tid; idx < C * D; idx += 256) {
        const int i = idx >> 7;
        const int d = idx & 127;
        sCtr[i * 129 + d] = centers[idx];
    }
    __syncthreads();

    float acc = 0.0f;
    for (int q = tid; q < C * C; q += 256) {
        const int i = q >> 6;
        const int j = q & 63;
        if (j > i) {
            const float* ci = sCtr + i * 129;
            const float* cj = sCtr + j * 129;
            float d2 = 0.0f;
            for (int d = 0; d < D; d++) {
                const float df = ci[d] - cj[d];
                d2 += df * df;
            }
            float h = 2.0f - d2;            // MARGIN = 2.0
            if (h < 0.0f) h = 0.0f;
            const float w = (i == 1 && j == 2) ? 2.0f : 1.0f;
            acc += w * h;
        }
    }

    double dacc = 0.0;
    for (int b = tid; b < nSq; b += 256) dacc += pSq[b];

    float wacc = 0.0f;
    if (tid < C) wacc = wc[tid];

    dred[tid] = (dacc - (double)wacc) * (1.0 / (double)BATCH)
              + (double)acc * (1.0 / (double)NPAIRS);
    __syncthreads();
    for (int o = 128; o > 0; o >>= 1) {
        if (tid < o) dred[tid] += dred[tid + o];
        __syncthreads();
    }
    if (tid == 0) out[0] = (float)dred[0];
}

extern "C" void kernel_launch(void* const* d_in, const int* in_sizes, int n_in,
                              void* d_out, int out_size, void* d_ws, size_t ws_size,
                              hipStream_t stream) {
    const float* feat    = (const float*)d_in[0];
    const int*   targets = (const int*)d_in[1];
    float* out = (float*)d_out;

    // workspace layout (~4.8 MB total; ws is 2 GB per harness fill)
    double* pSq      = (double*)d_ws;                   // [NACC]           8 KB
    float*  pSums    = (float*)(pSq + NACC);            // [NACC][D]      512 KB
    float*  centers  = pSums + (size_t)NACC * D;        // [C][D]          32 KB
    float*  wcv      = centers + C * D;                 // [C]
    int*    counts   = (int*)(wcv + C);                 // [C]
    int*    off      = counts + C;                      // [C+1]
    int*    bHist    = off + C + 1;                     // [NT][C]         64 KB
    int*    bBase    = bHist + NT * C;                  // [NT][C]         64 KB
    int*    idxSort  = bBase + NT * C;                  // [BATCH]          4 MB

    hist_kernel   <<<NT,   256, 0, stream>>>(targets, bHist);
    scan_kernel   <<<1,     64, 0, stream>>>(bHist, bBase, counts, off);
    scatter_kernel<<<NT,   256, 0, stream>>>(targets, bBase, idxSort);
    accum_kernel  <<<NACC, 256, 0, stream>>>(feat, idxSort, off, pSums, pSq);
    centers_kernel<<<C,    128, 0, stream>>>(pSums, counts, centers, wcv);
    stage3_kernel <<<1,    256, 0, stream>>>(centers, wcv, pSq, out, NACC);
}